// Round 8
// baseline (1554.488 us; speedup 1.0000x reference)
//
#include <hip/hip_runtime.h>

#define HID  256
#define TT   2048
#define NB   128
#define NTHR 1024

// DPP-based add of a rotated copy (VALU pipe, no LDS traffic).
// 0xB1 = quad_perm xor1, 0x4E = quad_perm xor2, 0x124 = row_ror:4, 0x128 = row_ror:8
template <int CTRL>
__device__ __forceinline__ float dpp_add(float v) {
    int t = __builtin_amdgcn_update_dpp(0, __float_as_int(v), CTRL, 0xF, 0xF, true);
    return v + __int_as_float(t);
}

__device__ __forceinline__ float tanh_fast(float x) {
    float e = __expf(2.0f * x);
    float r = __builtin_amdgcn_rcpf(e + 1.0f);
    return fmaf(-2.0f, r, 1.0f);
}

// Register-residency fight log:
//  r2: float4 array, 512thr/128w  -> VGPR=88, remat from L2 each step
//  r4: volatile float4 array      -> VGPR=84, array spilled to scratch
//  r5: + waves_per_eu(2,2)        -> VGPR=88, attr applied (SGPR 112), no help
//  r6: 128 NAMED scalars + pin    -> VGPR=88: RA SPILLED live-through values;
//      budget never became 256. 128w + ~60 working > 128-VGPR target => spill.
//  r7 (this): work WITH the 128-VGPR budget: 1024 threads, 64 weights/thread
//      (4 rows x 16 cols). 64 named+pinned + ~45 working ~= 110 < 128 =>
//      no pressure, no spill, weights finally VGPR-resident.

#define DECL_ROW(R) \
    float W##R##_0, W##R##_1, W##R##_2,  W##R##_3,  W##R##_4,  W##R##_5,  W##R##_6,  W##R##_7, \
          W##R##_8, W##R##_9, W##R##_10, W##R##_11, W##R##_12, W##R##_13, W##R##_14, W##R##_15;

#define LOAD_ROW(R) do { \
    const float4* wp_ = (const float4*)&W_hh[(4 * rg + R) * HID + 16 * c3]; \
    float4 a_ = wp_[0], b_ = wp_[1], c_ = wp_[2], d_ = wp_[3]; \
    W##R##_0  = a_.x; W##R##_1  = a_.y; W##R##_2  = a_.z; W##R##_3  = a_.w; \
    W##R##_4  = b_.x; W##R##_5  = b_.y; W##R##_6  = b_.z; W##R##_7  = b_.w; \
    W##R##_8  = c_.x; W##R##_9  = c_.y; W##R##_10 = c_.z; W##R##_11 = c_.w; \
    W##R##_12 = d_.x; W##R##_13 = d_.y; W##R##_14 = d_.z; W##R##_15 = d_.w; \
} while (0)

#define PIN_ROW(R) asm volatile("" \
    : "+v"(W##R##_0),  "+v"(W##R##_1),  "+v"(W##R##_2),  "+v"(W##R##_3), \
      "+v"(W##R##_4),  "+v"(W##R##_5),  "+v"(W##R##_6),  "+v"(W##R##_7), \
      "+v"(W##R##_8),  "+v"(W##R##_9),  "+v"(W##R##_10), "+v"(W##R##_11), \
      "+v"(W##R##_12), "+v"(W##R##_13), "+v"(W##R##_14), "+v"(W##R##_15))

#define FMA_ROW(R) do { \
    acc##R = fmaf(hx0,  W##R##_0,  acc##R); \
    acc##R = fmaf(hx1,  W##R##_1,  acc##R); \
    acc##R = fmaf(hx2,  W##R##_2,  acc##R); \
    acc##R = fmaf(hx3,  W##R##_3,  acc##R); \
    acc##R = fmaf(hx4,  W##R##_4,  acc##R); \
    acc##R = fmaf(hx5,  W##R##_5,  acc##R); \
    acc##R = fmaf(hx6,  W##R##_6,  acc##R); \
    acc##R = fmaf(hx7,  W##R##_7,  acc##R); \
    acc##R = fmaf(hx8,  W##R##_8,  acc##R); \
    acc##R = fmaf(hx9,  W##R##_9,  acc##R); \
    acc##R = fmaf(hx10, W##R##_10, acc##R); \
    acc##R = fmaf(hx11, W##R##_11, acc##R); \
    acc##R = fmaf(hx12, W##R##_12, acc##R); \
    acc##R = fmaf(hx13, W##R##_13, acc##R); \
    acc##R = fmaf(hx14, W##R##_14, acc##R); \
    acc##R = fmaf(hx15, W##R##_15, acc##R); \
} while (0)

#define RED16(A) do { \
    A = dpp_add<0xB1>(A); A = dpp_add<0x4E>(A); \
    A = dpp_add<0x124>(A); A = dpp_add<0x128>(A); \
} while (0)

__global__ __launch_bounds__(NTHR, 1)
void rnn_persist(
    const float* __restrict__ x,      // [B, T, 1]
    const float* __restrict__ W_ih,   // [256, 1]
    const float* __restrict__ W_hh,   // [256, 256]
    const float* __restrict__ b_ih,   // [256]
    const float* __restrict__ b_hh,   // [256]
    const float* __restrict__ W_out,  // [1, 256]
    const float* __restrict__ b_out,  // [1]
    float* __restrict__ y)            // [B, T, 1]
{
    // h: 8 chunks of 32 floats padded to 36 words (2-way aliasing ~free m136)
    __shared__ __align__(16) float s_h[2][8 * 36];
    __shared__ float s_x[TT];
    __shared__ float s_part[2][16];

    const int tid  = threadIdx.x;
    const int c3   = tid & 15;   // col chunk (16 cols)
    const int rg   = tid >> 4;   // row group (4 rows), 0..63
    const int lane = tid & 63;
    const int wv   = tid >> 6;   // wave 0..15
    const int b    = blockIdx.x;

    for (int k = tid; k < TT; k += NTHR) s_x[k] = x[(size_t)b * TT + k];

    DECL_ROW(0) DECL_ROW(1) DECL_ROW(2) DECL_ROW(3)
    LOAD_ROW(0); LOAD_ROW(1); LOAD_ROW(2); LOAD_ROW(3);
    PIN_ROW(0); PIN_ROW(1); PIN_ROW(2); PIN_ROW(3);

    const int   myrow = 4 * rg + (c3 & 3);   // row this lane finalizes (c3<4)
    const float wih   = W_ih[myrow];
    const float bias  = b_ih[myrow] + b_hh[myrow];
    const float wo_my = W_out[myrow];
    const float bout  = b_out[0];

    if (tid < 256) {
        int wd = 36 * (tid >> 5) + (tid & 31);
        s_h[0][wd] = 0.0f;
        s_h[1][wd] = 0.0f;
    }
    __syncthreads();

    int p = 0;
    float* yrow = y + (size_t)b * TT;
    const int hwword = 36 * (myrow >> 5) + (myrow & 31);   // h write addr
    const int rdbase = 36 * (c3 >> 1) + 16 * (c3 & 1);     // h read base

    for (int step = 0; step <= TT; ++step) {
        // finalize y_{step-1}: rotating wave sums the 16 per-wave partials
        if (step >= 1 && wv == ((step - 1) & 15)) {
            float pp = s_part[(step - 1) & 1][lane & 15];  // banks 0..15, b'cast
            pp = dpp_add<0xB1>(pp);
            pp = dpp_add<0x4E>(pp);
            pp = dpp_add<0x124>(pp);
            pp = dpp_add<0x128>(pp);
            if (lane == 0) yrow[step - 1] = pp + bout;
        }
        if (step == TT) break;

        const float xt = s_x[step];
        const float* hb = &s_h[p][rdbase];
        const float4 H0 = *(const float4*)(hb);
        const float4 H1 = *(const float4*)(hb + 4);
        const float4 H2 = *(const float4*)(hb + 8);
        const float4 H3 = *(const float4*)(hb + 12);
        const float hx0 = H0.x, hx1 = H0.y, hx2  = H0.z, hx3  = H0.w;
        const float hx4 = H1.x, hx5 = H1.y, hx6  = H1.z, hx7  = H1.w;
        const float hx8 = H2.x, hx9 = H2.y, hx10 = H2.z, hx11 = H2.w;
        const float hx12 = H3.x, hx13 = H3.y, hx14 = H3.z, hx15 = H3.w;

        float acc0 = 0.0f, acc1 = 0.0f, acc2 = 0.0f, acc3 = 0.0f;
        FMA_ROW(0); FMA_ROW(1); FMA_ROW(2); FMA_ROW(3);

        RED16(acc0); RED16(acc1); RED16(acc2); RED16(acc3);

        // lane picks its row total (bits work for all c3; only c3<4 used)
        float s01 = (c3 & 1) ? acc1 : acc0;
        float s23 = (c3 & 1) ? acc3 : acc2;
        float dot = (c3 & 2) ? s23 : s01;
        float hn  = tanh_fast(fmaf(xt, wih, bias) + dot);

        if ((c3 & 12) == 0) s_h[p ^ 1][hwword] = hn;   // c3 < 4

        // symmetric per-wave y partial: each wave owns 16 rows
        float pv = ((c3 & 12) == 0) ? hn * wo_my : 0.0f;
        pv = dpp_add<0xB1>(pv);
        pv = dpp_add<0x4E>(pv);
        pv = dpp_add<0x124>(pv);
        pv = dpp_add<0x128>(pv);
        pv += __shfl_xor(pv, 16);
        pv += __shfl_xor(pv, 32);
        if (lane == 0) s_part[step & 1][wv] = pv;

        __syncthreads();
        p ^= 1;
    }
}

extern "C" void kernel_launch(void* const* d_in, const int* in_sizes, int n_in,
                              void* d_out, int out_size, void* d_ws, size_t ws_size,
                              hipStream_t stream) {
    const float* x     = (const float*)d_in[0];
    const float* W_ih  = (const float*)d_in[1];
    const float* W_hh  = (const float*)d_in[2];
    const float* b_ih  = (const float*)d_in[3];
    const float* b_hh  = (const float*)d_in[4];
    const float* W_out = (const float*)d_in[5];
    const float* b_out = (const float*)d_in[6];
    float* y = (float*)d_out;

    hipLaunchKernelGGL(rnn_persist, dim3(NB), dim3(NTHR), 0, stream,
                       x, W_ih, W_hh, b_ih, b_hh, W_out, b_out, y);
}

// Round 9
// 1501.763 us; speedup vs baseline: 1.0351x; 1.0351x over previous
//
#include <hip/hip_runtime.h>

#define HID  256
#define TT   2048
#define NB   128
#define NTHR 1024

// DPP-based add of a rotated/broadcast copy (VALU pipe, no LDS traffic).
// 0xB1 quad_perm xor1, 0x4E quad_perm xor2, 0x124 row_ror:4, 0x128 row_ror:8,
// 0x142 row_bcast15 (lane15->lanes16-31, lane47->lanes48-63),
// 0x143 row_bcast31 (lane31->lanes32-63)
template <int CTRL>
__device__ __forceinline__ float dpp_add(float v) {
    int t = __builtin_amdgcn_update_dpp(0, __float_as_int(v), CTRL, 0xF, 0xF, true);
    return v + __int_as_float(t);
}

__device__ __forceinline__ float tanh_fast(float x) {
    float e = __expf(2.0f * x);
    float r = __builtin_amdgcn_rcpf(e + 1.0f);
    return fmaf(-2.0f, r, 1.0f);
}

// Register-residency fight log:
//  r2: float4 array, 512t/128w   -> VGPR=88, remat from L2 each step
//  r4: volatile float4 array     -> VGPR=84, spilled to scratch
//  r5: + waves_per_eu(2,2)       -> VGPR=88, attr ignored for budget
//  r6: 128 NAMED scalars + pin   -> VGPR=88, RA spilled live-through values
//  r7: 1024t, 64 named+pinned    -> VGPR=44: with 10.75KB LDS, TWO blocks fit
//      per CU -> achievable 8 waves/SIMD -> RA budget 64 VGPR -> spill.
//  => model: VGPR budget = 512 / max ACHIEVABLE waves-per-SIMD. None of the
//     attributes change achievability. LDS does. This round: dead 88KB LDS
//     pad -> 1 block/CU -> 4 waves/SIMD -> budget 128. Pressure ~110 < 128
//     -> weights finally stay resident. Runtime occupancy unchanged (grid
//     was already 1 block/CU); codegen-only effect.

#define DECL_ROW(R) \
    float W##R##_0, W##R##_1, W##R##_2,  W##R##_3,  W##R##_4,  W##R##_5,  W##R##_6,  W##R##_7, \
          W##R##_8, W##R##_9, W##R##_10, W##R##_11, W##R##_12, W##R##_13, W##R##_14, W##R##_15;

#define LOAD_ROW(R) do { \
    const float4* wp_ = (const float4*)&W_hh[(4 * rg + R) * HID + 16 * c3]; \
    float4 a_ = wp_[0], b_ = wp_[1], c_ = wp_[2], d_ = wp_[3]; \
    W##R##_0  = a_.x; W##R##_1  = a_.y; W##R##_2  = a_.z; W##R##_3  = a_.w; \
    W##R##_4  = b_.x; W##R##_5  = b_.y; W##R##_6  = b_.z; W##R##_7  = b_.w; \
    W##R##_8  = c_.x; W##R##_9  = c_.y; W##R##_10 = c_.z; W##R##_11 = c_.w; \
    W##R##_12 = d_.x; W##R##_13 = d_.y; W##R##_14 = d_.z; W##R##_15 = d_.w; \
} while (0)

#define PIN_ROW(R) asm volatile("" \
    : "+v"(W##R##_0),  "+v"(W##R##_1),  "+v"(W##R##_2),  "+v"(W##R##_3), \
      "+v"(W##R##_4),  "+v"(W##R##_5),  "+v"(W##R##_6),  "+v"(W##R##_7), \
      "+v"(W##R##_8),  "+v"(W##R##_9),  "+v"(W##R##_10), "+v"(W##R##_11), \
      "+v"(W##R##_12), "+v"(W##R##_13), "+v"(W##R##_14), "+v"(W##R##_15))

#define FMA_ROW(R) do { \
    acc##R = fmaf(hx0,  W##R##_0,  acc##R); \
    acc##R = fmaf(hx1,  W##R##_1,  acc##R); \
    acc##R = fmaf(hx2,  W##R##_2,  acc##R); \
    acc##R = fmaf(hx3,  W##R##_3,  acc##R); \
    acc##R = fmaf(hx4,  W##R##_4,  acc##R); \
    acc##R = fmaf(hx5,  W##R##_5,  acc##R); \
    acc##R = fmaf(hx6,  W##R##_6,  acc##R); \
    acc##R = fmaf(hx7,  W##R##_7,  acc##R); \
    acc##R = fmaf(hx8,  W##R##_8,  acc##R); \
    acc##R = fmaf(hx9,  W##R##_9,  acc##R); \
    acc##R = fmaf(hx10, W##R##_10, acc##R); \
    acc##R = fmaf(hx11, W##R##_11, acc##R); \
    acc##R = fmaf(hx12, W##R##_12, acc##R); \
    acc##R = fmaf(hx13, W##R##_13, acc##R); \
    acc##R = fmaf(hx14, W##R##_14, acc##R); \
    acc##R = fmaf(hx15, W##R##_15, acc##R); \
} while (0)

#define RED16(A) do { \
    A = dpp_add<0xB1>(A); A = dpp_add<0x4E>(A); \
    A = dpp_add<0x124>(A); A = dpp_add<0x128>(A); \
} while (0)

__global__ __launch_bounds__(NTHR, 4)
void rnn_persist(
    const float* __restrict__ x,      // [B, T, 1]
    const float* __restrict__ W_ih,   // [256, 1]
    const float* __restrict__ W_hh,   // [256, 256]
    const float* __restrict__ b_ih,   // [256]
    const float* __restrict__ b_hh,   // [256]
    const float* __restrict__ W_out,  // [1, 256]
    const float* __restrict__ b_out,  // [1]
    float* __restrict__ y)            // [B, T, 1]
{
    // h: 8 chunks of 32 floats padded to 36 words (2-way aliasing ~free m136)
    __shared__ __align__(16) float s_h[2][8 * 36];
    __shared__ float s_x[TT];
    __shared__ float s_part[2][16];
    // occupancy clamp: push block LDS > 80KB so only ONE block fits per CU
    // -> achievable occupancy 4 waves/SIMD -> RA VGPR budget 128.
    __shared__ float s_pad[22528];   // 88 KB, never touched at runtime

    const int tid  = threadIdx.x;
    const int c3   = tid & 15;   // col chunk (16 cols)
    const int rg   = tid >> 4;   // row group (4 rows), 0..63
    const int lane = tid & 63;
    const int wv   = tid >> 6;   // wave 0..15
    const int b    = blockIdx.x;

    if (b == 0x7fffffff) s_pad[tid] = 1.0f;   // opaque guard: keeps s_pad alive

    for (int k = tid; k < TT; k += NTHR) s_x[k] = x[(size_t)b * TT + k];

    DECL_ROW(0) DECL_ROW(1) DECL_ROW(2) DECL_ROW(3)
    LOAD_ROW(0); LOAD_ROW(1); LOAD_ROW(2); LOAD_ROW(3);
    PIN_ROW(0); PIN_ROW(1); PIN_ROW(2); PIN_ROW(3);

    const int   myrow = 4 * rg + (c3 & 3);   // row this lane finalizes (c3<4)
    const float wih   = W_ih[myrow];
    const float bias  = b_ih[myrow] + b_hh[myrow];
    const float wo_my = W_out[myrow];
    const float bout  = b_out[0];

    if (tid < 256) {
        int wd = 36 * (tid >> 5) + (tid & 31);
        s_h[0][wd] = 0.0f;
        s_h[1][wd] = 0.0f;
    }
    __syncthreads();

    int p = 0;
    float* yrow = y + (size_t)b * TT;
    const int hwword = 36 * (myrow >> 5) + (myrow & 31);   // h write addr
    const int rdbase = 36 * (c3 >> 1) + 16 * (c3 & 1);     // h read base

    for (int step = 0; step <= TT; ++step) {
        // finalize y_{step-1}: rotating wave sums the 16 per-wave partials
        if (step >= 1 && wv == ((step - 1) & 15)) {
            float pp = s_part[(step - 1) & 1][lane & 15];  // banks 0..15, b'cast
            pp = dpp_add<0xB1>(pp);
            pp = dpp_add<0x4E>(pp);
            pp = dpp_add<0x124>(pp);
            pp = dpp_add<0x128>(pp);
            if (lane == 0) yrow[step - 1] = pp + bout;
        }
        if (step == TT) break;

        const float xt = s_x[step];
        const float* hb = &s_h[p][rdbase];
        const float4 H0 = *(const float4*)(hb);
        const float4 H1 = *(const float4*)(hb + 4);
        const float4 H2 = *(const float4*)(hb + 8);
        const float4 H3 = *(const float4*)(hb + 12);
        const float hx0 = H0.x, hx1 = H0.y, hx2  = H0.z, hx3  = H0.w;
        const float hx4 = H1.x, hx5 = H1.y, hx6  = H1.z, hx7  = H1.w;
        const float hx8 = H2.x, hx9 = H2.y, hx10 = H2.z, hx11 = H2.w;
        const float hx12 = H3.x, hx13 = H3.y, hx14 = H3.z, hx15 = H3.w;

        float acc0 = 0.0f, acc1 = 0.0f, acc2 = 0.0f, acc3 = 0.0f;
        FMA_ROW(0); FMA_ROW(1); FMA_ROW(2); FMA_ROW(3);

        RED16(acc0); RED16(acc1); RED16(acc2); RED16(acc3);

        // lane picks its row total
        float s01 = (c3 & 1) ? acc1 : acc0;
        float s23 = (c3 & 1) ? acc3 : acc2;
        float dot = (c3 & 2) ? s23 : s01;
        float hn  = tanh_fast(fmaf(xt, wih, bias) + dot);

        if ((c3 & 12) == 0) s_h[p ^ 1][hwword] = hn;   // c3 < 4

        // symmetric per-wave y partial: each wave owns 16 rows (c3<4 lanes)
        float pv = ((c3 & 12) == 0) ? hn * wo_my : 0.0f;
        pv = dpp_add<0xB1>(pv);
        pv = dpp_add<0x4E>(pv);
        pv = dpp_add<0x124>(pv);
        pv = dpp_add<0x128>(pv);
        pv = dpp_add<0x142>(pv);   // row_bcast15: row1 += row0, row3 += row2
        pv = dpp_add<0x143>(pv);   // row_bcast31: rows2-3 += (row0+row1)
        if (lane == 63) s_part[step & 1][wv] = pv;   // lane63 holds full sum

        __syncthreads();
        p ^= 1;
    }
}

extern "C" void kernel_launch(void* const* d_in, const int* in_sizes, int n_in,
                              void* d_out, int out_size, void* d_ws, size_t ws_size,
                              hipStream_t stream) {
    const float* x     = (const float*)d_in[0];
    const float* W_ih  = (const float*)d_in[1];
    const float* W_hh  = (const float*)d_in[2];
    const float* b_ih  = (const float*)d_in[3];
    const float* b_hh  = (const float*)d_in[4];
    const float* W_out = (const float*)d_in[5];
    const float* b_out = (const float*)d_in[6];
    float* y = (float*)d_out;

    hipLaunchKernelGGL(rnn_persist, dim3(NB), dim3(NTHR), 0, stream,
                       x, W_ih, W_hh, b_ih, b_hh, W_out, b_out, y);
}

// Round 10
// 1457.830 us; speedup vs baseline: 1.0663x; 1.0301x over previous
//
#include <hip/hip_runtime.h>

#define HID  256
#define TT   2048
#define NB   128
#define NTHR 1024

// DPP-based add of a rotated/broadcast copy (VALU pipe, no LDS traffic).
// 0xB1 quad_perm xor1, 0x4E quad_perm xor2, 0x124 row_ror:4, 0x128 row_ror:8,
// 0x142 row_bcast15, 0x143 row_bcast31
template <int CTRL>
__device__ __forceinline__ float dpp_add(float v) {
    int t = __builtin_amdgcn_update_dpp(0, __float_as_int(v), CTRL, 0xF, 0xF, true);
    return v + __int_as_float(t);
}

__device__ __forceinline__ float tanh_fast(float x) {
    float e = __expf(2.0f * x);
    float r = __builtin_amdgcn_rcpf(e + 1.0f);
    return fmaf(-2.0f, r, 1.0f);
}

// Register-residency fight log:
//  r2: float4 array, 512t/128w   -> VGPR=88, remat from L2 each step
//  r4: volatile float4 array     -> VGPR=84, spilled to scratch
//  r5: + waves_per_eu(2,2)       -> VGPR=88, attr ignored for budget
//  r6: 128 NAMED scalars + pin   -> VGPR=88, RA spilled live-through values
//  r7: 1024t, 64 named+pinned    -> VGPR=44: 2 blocks/CU achievable ->
//      8 waves/SIMD target -> 64-VGPR budget -> spill (VALUBusy*dur == VALU
//      floor confirms other half of step is spill-reload stream)
//  r8: + 88KB LDS pad, guarded STORE only -> pad DSE'd (store never read),
//      LDS_Block_Size stayed 10752 -> clamp never applied, VGPR still 44.
//  r9 (this): pad kept alive via volatile write+read feeding a global store
//      under an unprovable guard. LDS ~99KB -> 1 block/CU -> 4 waves/SIMD
//      achievable -> RA budget 128 -> 64 pinned weights + ~45 working fits.
//      Runtime occupancy unchanged (grid already 1 block/CU).

#define DECL_ROW(R) \
    float W##R##_0, W##R##_1, W##R##_2,  W##R##_3,  W##R##_4,  W##R##_5,  W##R##_6,  W##R##_7, \
          W##R##_8, W##R##_9, W##R##_10, W##R##_11, W##R##_12, W##R##_13, W##R##_14, W##R##_15;

#define LOAD_ROW(R) do { \
    const float4* wp_ = (const float4*)&W_hh[(4 * rg + R) * HID + 16 * c3]; \
    float4 a_ = wp_[0], b_ = wp_[1], c_ = wp_[2], d_ = wp_[3]; \
    W##R##_0  = a_.x; W##R##_1  = a_.y; W##R##_2  = a_.z; W##R##_3  = a_.w; \
    W##R##_4  = b_.x; W##R##_5  = b_.y; W##R##_6  = b_.z; W##R##_7  = b_.w; \
    W##R##_8  = c_.x; W##R##_9  = c_.y; W##R##_10 = c_.z; W##R##_11 = c_.w; \
    W##R##_12 = d_.x; W##R##_13 = d_.y; W##R##_14 = d_.z; W##R##_15 = d_.w; \
} while (0)

#define PIN_ROW(R) asm volatile("" \
    : "+v"(W##R##_0),  "+v"(W##R##_1),  "+v"(W##R##_2),  "+v"(W##R##_3), \
      "+v"(W##R##_4),  "+v"(W##R##_5),  "+v"(W##R##_6),  "+v"(W##R##_7), \
      "+v"(W##R##_8),  "+v"(W##R##_9),  "+v"(W##R##_10), "+v"(W##R##_11), \
      "+v"(W##R##_12), "+v"(W##R##_13), "+v"(W##R##_14), "+v"(W##R##_15))

#define FMA_ROW(R) do { \
    acc##R = fmaf(hx0,  W##R##_0,  acc##R); \
    acc##R = fmaf(hx1,  W##R##_1,  acc##R); \
    acc##R = fmaf(hx2,  W##R##_2,  acc##R); \
    acc##R = fmaf(hx3,  W##R##_3,  acc##R); \
    acc##R = fmaf(hx4,  W##R##_4,  acc##R); \
    acc##R = fmaf(hx5,  W##R##_5,  acc##R); \
    acc##R = fmaf(hx6,  W##R##_6,  acc##R); \
    acc##R = fmaf(hx7,  W##R##_7,  acc##R); \
    acc##R = fmaf(hx8,  W##R##_8,  acc##R); \
    acc##R = fmaf(hx9,  W##R##_9,  acc##R); \
    acc##R = fmaf(hx10, W##R##_10, acc##R); \
    acc##R = fmaf(hx11, W##R##_11, acc##R); \
    acc##R = fmaf(hx12, W##R##_12, acc##R); \
    acc##R = fmaf(hx13, W##R##_13, acc##R); \
    acc##R = fmaf(hx14, W##R##_14, acc##R); \
    acc##R = fmaf(hx15, W##R##_15, acc##R); \
} while (0)

#define RED16(A) do { \
    A = dpp_add<0xB1>(A); A = dpp_add<0x4E>(A); \
    A = dpp_add<0x124>(A); A = dpp_add<0x128>(A); \
} while (0)

__global__ __launch_bounds__(NTHR)
void rnn_persist(
    const float* __restrict__ x,      // [B, T, 1]
    const float* __restrict__ W_ih,   // [256, 1]
    const float* __restrict__ W_hh,   // [256, 256]
    const float* __restrict__ b_ih,   // [256]
    const float* __restrict__ b_hh,   // [256]
    const float* __restrict__ W_out,  // [1, 256]
    const float* __restrict__ b_out,  // [1]
    float* __restrict__ y)            // [B, T, 1]
{
    // h: 8 chunks of 32 floats padded to 36 words (2-way aliasing ~free m136)
    __shared__ __align__(16) float s_h[2][8 * 36];
    __shared__ float s_x[TT];
    __shared__ float s_part[2][16];
    // occupancy clamp: block LDS > 80KB so only ONE block fits per CU ->
    // achievable occupancy 4 waves/SIMD -> RA VGPR budget 128.
    __shared__ float s_pad[22528];   // 88 KB

    const int tid  = threadIdx.x;
    const int c3   = tid & 15;   // col chunk (16 cols)
    const int rg   = tid >> 4;   // row group (4 rows), 0..63
    const int lane = tid & 63;
    const int wv   = tid >> 6;   // wave 0..15
    const int b    = blockIdx.x;

    // keep s_pad alive: volatile write + volatile read feeding an observable
    // global store, under a guard the compiler cannot prove false (b < NB is
    // runtime knowledge only). Volatile accesses on a reachable path cannot
    // be deleted, so the array must be allocated. Never executes.
    if (b == -1) {
        volatile float* vp = s_pad;
        vp[tid] = 1.0f;
        y[tid] = vp[tid];
    }

    for (int k = tid; k < TT; k += NTHR) s_x[k] = x[(size_t)b * TT + k];

    DECL_ROW(0) DECL_ROW(1) DECL_ROW(2) DECL_ROW(3)
    LOAD_ROW(0); LOAD_ROW(1); LOAD_ROW(2); LOAD_ROW(3);
    PIN_ROW(0); PIN_ROW(1); PIN_ROW(2); PIN_ROW(3);

    const int   myrow = 4 * rg + (c3 & 3);   // row this lane finalizes (c3<4)
    const float wih   = W_ih[myrow];
    const float bias  = b_ih[myrow] + b_hh[myrow];
    const float wo_my = W_out[myrow];
    const float bout  = b_out[0];

    if (tid < 256) {
        int wd = 36 * (tid >> 5) + (tid & 31);
        s_h[0][wd] = 0.0f;
        s_h[1][wd] = 0.0f;
    }
    __syncthreads();

    int p = 0;
    float* yrow = y + (size_t)b * TT;
    const int hwword = 36 * (myrow >> 5) + (myrow & 31);   // h write addr
    const int rdbase = 36 * (c3 >> 1) + 16 * (c3 & 1);     // h read base

    for (int step = 0; step <= TT; ++step) {
        // finalize y_{step-1}: rotating wave sums the 16 per-wave partials
        if (step >= 1 && wv == ((step - 1) & 15)) {
            float pp = s_part[(step - 1) & 1][lane & 15];  // banks 0..15, b'cast
            pp = dpp_add<0xB1>(pp);
            pp = dpp_add<0x4E>(pp);
            pp = dpp_add<0x124>(pp);
            pp = dpp_add<0x128>(pp);
            if (lane == 0) yrow[step - 1] = pp + bout;
        }
        if (step == TT) break;

        const float xt = s_x[step];
        const float* hb = &s_h[p][rdbase];
        const float4 H0 = *(const float4*)(hb);
        const float4 H1 = *(const float4*)(hb + 4);
        const float4 H2 = *(const float4*)(hb + 8);
        const float4 H3 = *(const float4*)(hb + 12);
        const float hx0 = H0.x, hx1 = H0.y, hx2  = H0.z, hx3  = H0.w;
        const float hx4 = H1.x, hx5 = H1.y, hx6  = H1.z, hx7  = H1.w;
        const float hx8 = H2.x, hx9 = H2.y, hx10 = H2.z, hx11 = H2.w;
        const float hx12 = H3.x, hx13 = H3.y, hx14 = H3.z, hx15 = H3.w;

        float acc0 = 0.0f, acc1 = 0.0f, acc2 = 0.0f, acc3 = 0.0f;
        FMA_ROW(0); FMA_ROW(1); FMA_ROW(2); FMA_ROW(3);

        RED16(acc0); RED16(acc1); RED16(acc2); RED16(acc3);

        // lane picks its row total
        float s01 = (c3 & 1) ? acc1 : acc0;
        float s23 = (c3 & 1) ? acc3 : acc2;
        float dot = (c3 & 2) ? s23 : s01;
        float hn  = tanh_fast(fmaf(xt, wih, bias) + dot);

        if ((c3 & 12) == 0) s_h[p ^ 1][hwword] = hn;   // c3 < 4

        // symmetric per-wave y partial: each wave owns 16 rows (c3<4 lanes)
        float pv = ((c3 & 12) == 0) ? hn * wo_my : 0.0f;
        pv = dpp_add<0xB1>(pv);
        pv = dpp_add<0x4E>(pv);
        pv = dpp_add<0x124>(pv);
        pv = dpp_add<0x128>(pv);
        pv = dpp_add<0x142>(pv);   // row_bcast15
        pv = dpp_add<0x143>(pv);   // row_bcast31 -> lane63 holds full sum
        if (lane == 63) s_part[step & 1][wv] = pv;

        __syncthreads();
        p ^= 1;
    }
}

extern "C" void kernel_launch(void* const* d_in, const int* in_sizes, int n_in,
                              void* d_out, int out_size, void* d_ws, size_t ws_size,
                              hipStream_t stream) {
    const float* x     = (const float*)d_in[0];
    const float* W_ih  = (const float*)d_in[1];
    const float* W_hh  = (const float*)d_in[2];
    const float* b_ih  = (const float*)d_in[3];
    const float* b_hh  = (const float*)d_in[4];
    const float* W_out = (const float*)d_in[5];
    const float* b_out = (const float*)d_in[6];
    float* y = (float*)d_out;

    hipLaunchKernelGGL(rnn_persist, dim3(NB), dim3(NTHR), 0, stream,
                       x, W_ih, W_hh, b_ih, b_hh, W_out, b_out, y);
}